// Round 13
// baseline (85.737 us; speedup 1.0000x reference)
//
#include <hip/hip_runtime.h>
#include <stdint.h>

#define HV 384
#define WV 384
#define HF 96
#define WF 96
#define NC 128
#define NB 32
#define NSTORM 50
#define TFRAMES 12
#define MIN_INT 0.3f

// peak tile geometry
#define TW 64
#define TH 32
#define GX (WV / TW)          // 6
#define GY (HV / TH)          // 12
#define GT (GX * GY)          // 72 tiles per batch
#define LCAP 256              // >= provable max peaks per tile (~153)

// selection
#define CCAP 1536             // collect buffer (expected ~950 used — measured
                              // distribution: ~39% of keys share the top
                              // 16-bit bin, hence two-level refinement below)
// projection
#define SPB 10
#define NGRP (NSTORM / SPB)   // 5 groups per batch
#define NPROJ (NB * NGRP)     // 160 blocks  (<= 256 CUs: single block-wave)

__device__ __forceinline__ int reflect_idx(int g, int n) {
    if (g < 0) return -g - 1;
    if (g >= n) return 2 * n - 1 - g;
    return g;
}

__device__ __forceinline__ int h1bin(uint32_t u) {
    int bin = (int)(u >> 16) - 0x3E99;
    return bin < 0 ? 0 : (bin > 255 ? 255 : bin);
}

// ---- slow scalar peak predicate, used only on the dead fallback path
__device__ __forceinline__ bool is_peak(const float* __restrict__ vb, int p) {
    int i = p / WV, j = p % WV;
    float v = vb[p];
    if (!(v > MIN_INT)) return false;
    for (int dr = -4; dr <= 3; ++dr) {
        const float* row = vb + reflect_idx(i + dr, HV) * WV;
        for (int dc = -4; dc <= 3; ++dc)
            if (row[reflect_idx(j + dc, WV)] > v) return false;
    }
    return true;
}

// ---- kernel 1: separable 8x8 max filter on LDS tiles; float4 staging;
// per-tile candidate slots (no global atomics, no memset). key =
// (float_bits(v)<<32) | ~idx — strict total order -> deterministic selection.
__global__ void peak_kernel(const float* __restrict__ vil,
                            uint64_t* __restrict__ cand,
                            int* __restrict__ tcnt) {
    __shared__ __align__(16) float A[TH + 7][TW + 8];  // tile + halo
    __shared__ float Bm[TH + 7][TW];                   // horizontal max
    __shared__ uint64_t lkeys[LCAP];
    __shared__ int lcnt;

    int b = blockIdx.z, bx = blockIdx.x;
    int tx0 = bx * TW, ty0 = blockIdx.y * TH;
    int tile = blockIdx.y * GX + bx;
    int tid = threadIdx.x;                 // 256 threads
    const float* vb = vil + ((size_t)b * TFRAMES + (TFRAMES - 1)) * (HV * WV);

    if (tid == 0) lcnt = 0;

    int c0   = (bx == 0) ? 0 : tx0 - 4;               // multiple of 4
    int nf4  = (bx == 0 || bx == GX - 1) ? 17 : 18;
    int aoff = c0 - (tx0 - 4);                        // 0 or 4
    for (int k = tid; k < (TH + 7) * nf4; k += 256) {
        int r = k / nf4, q = k - r * nf4;
        int gr = reflect_idx(ty0 + r - 4, HV);
        float4 vv = *(const float4*)(vb + (size_t)gr * WV + c0 + 4 * q);
        *(float4*)&A[r][aoff + 4 * q] = vv;
    }
    int nl = aoff;
    int rstart = aoff + 4 * nf4;
    int nr = 71 - rstart; if (nr < 0) nr = 0;
    int ns = nl + nr;
    if (ns) for (int k = tid; k < (TH + 7) * ns; k += 256) {
        int r = k / ns, s = k - r * ns;
        int c = (s < nl) ? s : rstart + (s - nl);
        int gr = reflect_idx(ty0 + r - 4, HV);
        int gc = reflect_idx(tx0 + c - 4, WV);
        A[r][c] = vb[(size_t)gr * WV + gc];
    }
    __syncthreads();

    for (int k = tid; k < (TH + 7) * TW; k += 256) {
        int r = k / TW, c = k % TW;
        float m = A[r][c];
        #pragma unroll
        for (int d = 1; d < 8; ++d) m = fmaxf(m, A[r][c + d]);
        Bm[r][c] = m;
    }
    __syncthreads();

    for (int k = tid; k < TH * TW; k += 256) {
        int r = k / TW, c = k % TW;
        float v = A[r + 4][c + 4];
        if (v > MIN_INT) {
            float m = Bm[r][c];
            #pragma unroll
            for (int d = 1; d < 8; ++d) m = fmaxf(m, Bm[r + d][c]);
            if (m <= v) {                  // window max == v -> peak
                int p = (ty0 + r) * WV + (tx0 + c);
                uint64_t key = ((uint64_t)__float_as_uint(v) << 32)
                             | (uint64_t)(0xFFFFFFFFu - (uint32_t)p);
                int pos = atomicAdd(&lcnt, 1);        // LDS atomic only
                if (pos < LCAP) lkeys[pos] = key;
            }
        }
    }
    __syncthreads();

    int take = lcnt < LCAP ? lcnt : LCAP;
    if (tid == 0) tcnt[b * GT + tile] = take;
    uint64_t* dst = cand + (size_t)(b * GT + tile) * LCAP;
    for (int k = tid; k < take; k += 256) dst[k] = lkeys[k];
}

// ---- kernel 2: 160 blocks; block = (batch b, storm-group of 10).
// Redundant per-block select (deterministic), then project its 10 storms.
// Select v2: tile-major iteration (no binary search), two-level histogram
// (16-bit bins, then 8 more mantissa bits inside the cut bin) so the ranked
// set is ~60 keys, wave-aggregated ballot compaction.
__global__ void select_project_kernel(const uint64_t* __restrict__ cand,
                                      const int* __restrict__ tcnt,
                                      const float* __restrict__ vil,
                                      const float* __restrict__ features,
                                      const float* __restrict__ proj_w,
                                      const float* __restrict__ proj_b,
                                      float* __restrict__ out) {
    __shared__ uint64_t coll[CCAP];            // 12 KB
    __shared__ uint64_t keep[CCAP];            // 12 KB
    __shared__ int hist[256];
    __shared__ int rss[256];
    __shared__ int cnt_s[GT];
    __shared__ int sel_idx_s[NSTORM];
    __shared__ int sel_valid_s[NSTORM];
    __shared__ int n_s, ccnt, kcnt, j1_s, sgt_s, j2_s;
    __shared__ uint64_t wred[4];
    __shared__ uint64_t bcast;
    __shared__ __align__(16) float g[SPB][NC]; // 5 KB

    int blk = blockIdx.x;
    int b = blk / NGRP;
    int grp = blk % NGRP;
    int tid = threadIdx.x;                     // 256
    int lane = tid & 63;
    const uint64_t* cb = cand + (size_t)b * GT * LCAP;

    if (tid < GT) cnt_s[tid] = tcnt[b * GT + tid];
    hist[tid] = 0;
    if (tid == 0) { ccnt = 0; kcnt = 0; }
    __syncthreads();
    // n = sum of 72 counts (single-wave shuffle reduce)
    if (tid < 64) {
        int s = cnt_s[tid] + ((tid < GT - 64) ? cnt_s[64 + tid] : 0);
        #pragma unroll
        for (int off = 32; off > 0; off >>= 1) s += __shfl_xor(s, off);
        if (tid == 0) n_s = s;
    }
    __syncthreads();
    int n = n_s;
    int target = n < NSTORM ? n : NSTORM;

    if (n > 0) {
        // ---- pass A: histogram high-16-bit bins (read only high u32)
        for (int t = 0; t < GT; ++t) {
            int c = cnt_s[t];
            const uint32_t* hw = (const uint32_t*)(cb + (size_t)t * LCAP);
            for (int k = tid; k < c; k += 256)
                atomicAdd(&hist[h1bin(hw[2 * k + 1])], 1);
        }
        __syncthreads();
        rss[tid] = hist[255 - tid];
        __syncthreads();
        #pragma unroll
        for (int off = 1; off < 256; off <<= 1) {
            int v = (tid >= off) ? rss[tid - off] : 0;
            __syncthreads();
            rss[tid] += v;
            __syncthreads();
        }
        {   // j1 = max j with S[j] >= target;  S[j] = rss[255-j]
            int S_j  = rss[255 - tid];
            int S_j1 = (tid == 255) ? 0 : rss[254 - tid];
            if (S_j >= target && S_j1 < target) { j1_s = tid; sgt_s = S_j1; }
        }
        __syncthreads();
        int j1 = j1_s, sgt = sgt_s;

        // ---- collect keys with bin >= j1 (wave-aggregated atomic)
        for (int t = 0; t < GT; ++t) {
            int c = cnt_s[t];
            for (int k0 = 0; k0 < c; k0 += 256) {
                int k = k0 + tid;
                uint64_t key = 0; bool p = false;
                if (k < c) {
                    key = cb[(size_t)t * LCAP + k];
                    p = (h1bin((uint32_t)(key >> 32)) >= j1);
                }
                unsigned long long mask = __ballot(p);
                if (mask) {
                    int leader = __ffsll((long long)mask) - 1;
                    int base = 0;
                    if (lane == leader) base = atomicAdd(&ccnt, __popcll(mask));
                    base = __shfl(base, leader);
                    if (p) {
                        int pos = base + __popcll(mask & ((1ull << lane) - 1));
                        if (pos < CCAP) coll[pos] = key;
                    }
                }
            }
        }
        __syncthreads();
        int m = ccnt;

        if (m <= CCAP) {
            const uint64_t* P; int mm;
            if (m <= 256) {                // already small: rank directly
                P = coll; mm = m;
            } else {
                // ---- pass B: refine inside bin j1 by next 8 mantissa bits
                hist[tid] = 0;
                __syncthreads();
                for (int i = tid; i < m; i += 256) {
                    uint32_t u = (uint32_t)(coll[i] >> 32);
                    if (h1bin(u) == j1) atomicAdd(&hist[(u >> 8) & 0xFF], 1);
                }
                __syncthreads();
                rss[tid] = hist[255 - tid];
                __syncthreads();
                #pragma unroll
                for (int off = 1; off < 256; off <<= 1) {
                    int v = (tid >= off) ? rss[tid - off] : 0;
                    __syncthreads();
                    rss[tid] += v;
                    __syncthreads();
                }
                int k2 = target - sgt;     // >= 1
                {   // j2 = max j with SB[j] >= k2
                    int S_j  = rss[255 - tid];
                    int S_j1 = (tid == 255) ? 0 : rss[254 - tid];
                    if (S_j >= k2 && S_j1 < k2) j2_s = tid;
                }
                __syncthreads();
                int j2 = j2_s;
                // compact kept keys into keep[] (wave-aggregated)
                for (int i0 = 0; i0 < m; i0 += 256) {
                    int i = i0 + tid;
                    uint64_t key = 0; bool p = false;
                    if (i < m) {
                        key = coll[i];
                        uint32_t u = (uint32_t)(key >> 32);
                        int hh = h1bin(u);
                        p = (hh > j1) || (hh == j1 && ((u >> 8) & 0xFF) >= (uint32_t)j2);
                    }
                    unsigned long long mask = __ballot(p);
                    if (mask) {
                        int leader = __ffsll((long long)mask) - 1;
                        int base = 0;
                        if (lane == leader) base = atomicAdd(&kcnt, __popcll(mask));
                        base = __shfl(base, leader);
                        if (p) {
                            int pos = base + __popcll(mask & ((1ull << lane) - 1));
                            keep[pos] = key;   // kcnt <= ccnt <= CCAP
                        }
                    }
                }
                __syncthreads();
                P = keep; mm = kcnt;
            }
            // ---- rank kept keys; all keys greater than a kept key are kept,
            // so in-set rank == global rank. Write winners straight to rank.
            for (int i = tid; i < mm; i += 256) {
                uint64_t ki = P[i];
                int r = 0;
                for (int j = 0; j < mm; ++j) r += (P[j] > ki);
                if (r < target) {
                    sel_idx_s[r] = (int)(~(uint32_t)(ki & 0xFFFFFFFFu));
                    sel_valid_s[r] = 1;
                }
            }
        } else {
            // dead safety path (collect overflow): iterative rescan
            uint64_t prev = ~0ull;
            for (int t = 0; t < target; ++t) {
                uint64_t best = 0;
                for (int tt = 0; tt < GT; ++tt) {
                    int c = cnt_s[tt];
                    for (int k = tid; k < c; k += 256) {
                        uint64_t key = cb[(size_t)tt * LCAP + k];
                        if (key < prev && key > best) best = key;
                    }
                }
                #pragma unroll
                for (int off = 32; off > 0; off >>= 1) {
                    uint64_t o = __shfl_xor(best, off);
                    if (o > best) best = o;
                }
                if ((tid & 63) == 0) wred[tid >> 6] = best;
                __syncthreads();
                if (tid == 0) {
                    uint64_t w = wred[0];
                    #pragma unroll
                    for (int i = 1; i < 4; ++i) if (wred[i] > w) w = wred[i];
                    bcast = w;
                    sel_idx_s[t] = (int)(~(uint32_t)(w & 0xFFFFFFFFu));
                    sel_valid_s[t] = 1;
                }
                __syncthreads();
                prev = bcast;
            }
        }
    }
    __syncthreads();

    // dead fallback: <50 peaks -> ascending non-peak indices; none -> center
    if (tid == 0 && target < NSTORM) {
        const float* vb = vil + ((size_t)b * TFRAMES + (TFRAMES - 1)) * (HV * WV);
        int f = 0;
        for (int t = target; t < NSTORM; ++t) {
            while (f < HV * WV && is_peak(vb, f)) ++f;
            sel_idx_s[t] = f; sel_valid_s[t] = 0; ++f;
        }
        if (n == 0) { sel_idx_s[0] = (HV / 2) * WV + (WV / 2); sel_valid_s[0] = 1; }
    }
    __syncthreads();

    // positions / valid written once per batch (group 0 only)
    if (grp == 0 && tid < NSTORM) {
        int idx = sel_idx_s[tid], vld = sel_valid_s[tid];
        int y = idx / WV, x = idx % WV;
        int yf = y >> 2; if (yf > HF - 1) yf = HF - 1;
        int xf = x >> 2; if (xf > WF - 1) xf = WF - 1;
        float* pos_out   = out + (size_t)NB * NSTORM * NC;
        float* valid_out = pos_out + (size_t)NB * NSTORM * 2;
        pos_out[(b * NSTORM + tid) * 2 + 0] = (float)yf;
        pos_out[(b * NSTORM + tid) * 2 + 1] = (float)xf;
        valid_out[b * NSTORM + tid] = vld ? 1.f : 0.f;
    }

    // ---- project my 10 storms: gather (256 threads) + matvec (128)
    for (int q = tid; q < SPB * NC; q += 256) {
        int s = q >> 7, c = q & 127;
        int idx = sel_idx_s[grp * SPB + s];
        int y = idx / WV, x = idx % WV;
        int yf = y >> 2; if (yf > HF - 1) yf = HF - 1;
        int xf = x >> 2; if (xf > WF - 1) xf = WF - 1;
        g[s][c] = features[((size_t)b * NC + c) * (HF * WF) + yf * WF + xf];
    }
    __syncthreads();

    if (tid < NC) {
        int d = tid;
        const float4* w4 = (const float4*)(proj_w + (size_t)d * NC);
        float acc[SPB];
        #pragma unroll
        for (int s = 0; s < SPB; ++s) acc[s] = 0.f;
        for (int q = 0; q < 32; ++q) {
            float4 wv = w4[q];
            #pragma unroll
            for (int s = 0; s < SPB; ++s) {
                float4 gv = *(const float4*)&g[s][4 * q];
                acc[s] += gv.x * wv.x;
                acc[s] += gv.y * wv.y;
                acc[s] += gv.z * wv.z;
                acc[s] += gv.w * wv.w;
            }
        }
        float bias = proj_b[d];
        #pragma unroll
        for (int s = 0; s < SPB; ++s) {
            int m = grp * SPB + s;
            out[((size_t)b * NSTORM + m) * NC + d] =
                sel_valid_s[m] ? (acc[s] + bias) : 0.f;
        }
    }
}

extern "C" void kernel_launch(void* const* d_in, const int* in_sizes, int n_in,
                              void* d_out, int out_size, void* d_ws, size_t ws_size,
                              hipStream_t stream) {
    const float* features = (const float*)d_in[0];
    const float* vil      = (const float*)d_in[1];
    const float* proj_w   = (const float*)d_in[2];
    const float* proj_b   = (const float*)d_in[3];
    float* out = (float*)d_out;

    uint8_t* ws = (uint8_t*)d_ws;
    int* tcnt      = (int*)ws;                        // 32*72 ints, all written
    uint64_t* cand = (uint64_t*)(ws + 32768);         // 32*72*256 u64 = 4.7 MB

    dim3 gA(GX, GY, NB);                   // 6 x 12 x 32
    peak_kernel<<<gA, 256, 0, stream>>>(vil, cand, tcnt);
    select_project_kernel<<<NPROJ, 256, 0, stream>>>(cand, tcnt, vil, features,
                                                     proj_w, proj_b, out);
}

// Round 14
// 39.628 us; speedup vs baseline: 2.1635x; 2.1635x over previous
//
#include <hip/hip_runtime.h>
#include <stdint.h>

#define HV 384
#define WV 384
#define HF 96
#define WF 96
#define NC 128
#define NB 32
#define NSTORM 50
#define TFRAMES 12
#define MIN_INT 0.3f
#define THOT 0.999f           // hot-key threshold; E[hot/batch] ~ 143 >> 50

// peak tile geometry
#define TW 64
#define TH 32
#define GX (WV / TW)          // 6
#define GY (HV / TH)          // 12
#define GT (GX * GY)          // 72 tiles per batch
#define LCAP 256              // >= provable max peaks per tile (~153)

// selection
#define HCAP 1024             // hot staging (expected ~143)
// projection
#define SPB 10
#define NGRP (NSTORM / SPB)   // 5 groups per batch
#define NPROJ (NB * NGRP)     // 160 blocks (single block-wave on 256 CUs)

__device__ __forceinline__ int reflect_idx(int g, int n) {
    if (g < 0) return -g - 1;
    if (g >= n) return 2 * n - 1 - g;
    return g;
}

// ---- slow scalar peak predicate, used only on the dead fallback path
__device__ __forceinline__ bool is_peak(const float* __restrict__ vb, int p) {
    int i = p / WV, j = p % WV;
    float v = vb[p];
    if (!(v > MIN_INT)) return false;
    for (int dr = -4; dr <= 3; ++dr) {
        const float* row = vb + reflect_idx(i + dr, HV) * WV;
        for (int dc = -4; dc <= 3; ++dc)
            if (row[reflect_idx(j + dc, WV)] > v) return false;
    }
    return true;
}

// ---- kernel 1: separable 8x8 max filter; per-tile slots, keys partitioned
// hot-first (v >= THOT). tcnt packs (hot<<16)|total; every slot written every
// launch (no atomics, no memset). key = bits(v)<<32 | ~idx — strict total
// order; any hot key > any cold key, so top-50(hot) == top-50 when hot>=50.
__global__ void peak_kernel(const float* __restrict__ vil,
                            uint64_t* __restrict__ cand,
                            int* __restrict__ tcnt) {
    __shared__ __align__(16) float A[TH + 7][TW + 8];  // tile + halo
    __shared__ float Bm[TH + 7][TW];                   // horizontal max
    __shared__ uint64_t hkeys[LCAP];
    __shared__ uint64_t ckeys[LCAP];
    __shared__ int hcnt, ccnt;

    int b = blockIdx.z, bx = blockIdx.x;
    int tx0 = bx * TW, ty0 = blockIdx.y * TH;
    int tile = blockIdx.y * GX + bx;
    int tid = threadIdx.x;                 // 256 threads
    const float* vb = vil + ((size_t)b * TFRAMES + (TFRAMES - 1)) * (HV * WV);

    if (tid == 0) { hcnt = 0; ccnt = 0; }

    // float4 staging; row reflect is pointer-only, keeps 16B alignment.
    int c0   = (bx == 0) ? 0 : tx0 - 4;               // multiple of 4
    int nf4  = (bx == 0 || bx == GX - 1) ? 17 : 18;
    int aoff = c0 - (tx0 - 4);                        // 0 or 4
    for (int k = tid; k < (TH + 7) * nf4; k += 256) {
        int r = k / nf4, q = k - r * nf4;
        int gr = reflect_idx(ty0 + r - 4, HV);
        float4 vv = *(const float4*)(vb + (size_t)gr * WV + c0 + 4 * q);
        *(float4*)&A[r][aoff + 4 * q] = vv;
    }
    int nl = aoff;
    int rstart = aoff + 4 * nf4;
    int nr = 71 - rstart; if (nr < 0) nr = 0;
    int ns = nl + nr;
    if (ns) for (int k = tid; k < (TH + 7) * ns; k += 256) {
        int r = k / ns, s = k - r * ns;
        int c = (s < nl) ? s : rstart + (s - nl);
        int gr = reflect_idx(ty0 + r - 4, HV);
        int gc = reflect_idx(tx0 + c - 4, WV);
        A[r][c] = vb[(size_t)gr * WV + gc];
    }
    __syncthreads();

    // horizontal: Bm[r][c] = max(A[r][c..c+7])
    for (int k = tid; k < (TH + 7) * TW; k += 256) {
        int r = k / TW, c = k % TW;
        float m = A[r][c];
        #pragma unroll
        for (int d = 1; d < 8; ++d) m = fmaxf(m, A[r][c + d]);
        Bm[r][c] = m;
    }
    __syncthreads();

    // vertical + predicate
    for (int k = tid; k < TH * TW; k += 256) {
        int r = k / TW, c = k % TW;
        float v = A[r + 4][c + 4];
        if (v > MIN_INT) {
            float m = Bm[r][c];
            #pragma unroll
            for (int d = 1; d < 8; ++d) m = fmaxf(m, Bm[r + d][c]);
            if (m <= v) {                  // window max == v -> peak
                int p = (ty0 + r) * WV + (tx0 + c);
                uint64_t key = ((uint64_t)__float_as_uint(v) << 32)
                             | (uint64_t)(0xFFFFFFFFu - (uint32_t)p);
                if (v >= THOT) {
                    int pos = atomicAdd(&hcnt, 1);
                    if (pos < LCAP) hkeys[pos] = key;
                } else {
                    int pos = atomicAdd(&ccnt, 1);
                    if (pos < LCAP) ckeys[pos] = key;
                }
            }
        }
    }
    __syncthreads();

    int nh = hcnt < LCAP ? hcnt : LCAP;
    int nc = ccnt < LCAP - nh ? ccnt : LCAP - nh;     // nh+nc <= 153 < LCAP
    if (tid == 0) tcnt[b * GT + tile] = (nh << 16) | (nh + nc);
    uint64_t* dst = cand + (size_t)(b * GT + tile) * LCAP;
    for (int k = tid; k < nh; k += 256) dst[k] = hkeys[k];
    for (int k = tid; k < nc; k += 256) dst[nh + k] = ckeys[k];
}

// ---- kernel 2: 160 blocks; block = (batch b, storm-group of 10).
// Redundant per-block select (deterministic): gather ~143 hot keys flat into
// LDS, rank O(H^2) by LDS-broadcast compares, write winners to rank.
// Then project the block's 10 storms.
__global__ void select_project_kernel(const uint64_t* __restrict__ cand,
                                      const int* __restrict__ tcnt,
                                      const float* __restrict__ vil,
                                      const float* __restrict__ features,
                                      const float* __restrict__ proj_w,
                                      const float* __restrict__ proj_b,
                                      float* __restrict__ out) {
    __shared__ uint64_t hot[HCAP];             // 8 KB
    __shared__ int sc[128];
    __shared__ int hoffs[GT + 1];
    __shared__ int toffs[GT + 1];
    __shared__ int sel_idx_s[NSTORM];
    __shared__ int sel_valid_s[NSTORM];
    __shared__ uint64_t wred[4];
    __shared__ uint64_t bcast;
    __shared__ __align__(16) float g[SPB][NC]; // 5 KB

    int blk = blockIdx.x;
    int b = blk / NGRP;
    int grp = blk % NGRP;
    int tid = threadIdx.x;                     // 256
    const uint64_t* cb = cand + (size_t)b * GT * LCAP;

    int packed = (tid < GT) ? tcnt[b * GT + tid] : 0;
    int myhot = packed >> 16, mytot = packed & 0xFFFF;

    // scan hot counts
    if (tid < 128) sc[tid] = (tid < GT) ? myhot : 0;
    __syncthreads();
    #pragma unroll
    for (int off = 1; off < 128; off <<= 1) {
        int v = 0;
        if (tid < 128 && tid >= off) v = sc[tid - off];
        __syncthreads();
        if (tid < 128) sc[tid] += v;
        __syncthreads();
    }
    if (tid == 0) hoffs[0] = 0;
    if (tid < GT) hoffs[tid + 1] = sc[tid];
    __syncthreads();
    int H = hoffs[GT];

    // scan total counts
    if (tid < 128) sc[tid] = (tid < GT) ? mytot : 0;
    __syncthreads();
    #pragma unroll
    for (int off = 1; off < 128; off <<= 1) {
        int v = 0;
        if (tid < 128 && tid >= off) v = sc[tid - off];
        __syncthreads();
        if (tid < 128) sc[tid] += v;
        __syncthreads();
    }
    if (tid == 0) toffs[0] = 0;
    if (tid < GT) toffs[tid + 1] = sc[tid];
    __syncthreads();
    int n = toffs[GT];
    int target = n < NSTORM ? n : NSTORM;

    if (H >= target && H <= HCAP && n > 0) {
        // ---- fast path: gather hot keys flat (hot keys are at slot front)
        for (int hi = tid; hi < H; hi += 256) {
            int lo = 0, hi2 = GT;
            while (hi2 - lo > 1) { int mid = (lo + hi2) >> 1;
                                   if (hoffs[mid] <= hi) lo = mid; else hi2 = mid; }
            hot[hi] = cb[(size_t)lo * LCAP + (hi - hoffs[lo])];
        }
        __syncthreads();
        // ---- rank (keys unique; hot set contains all keys >= any hot key)
        for (int i = tid; i < H; i += 256) {
            uint64_t ki = hot[i];
            int r = 0;
            for (int j = 0; j < H; ++j) r += (hot[j] > ki);
            if (r < target) {
                sel_idx_s[r] = (int)(~(uint32_t)(ki & 0xFFFFFFFFu));
                sel_valid_s[r] = 1;
            }
        }
    } else if (n > 0) {
        // dead safety path (H < target or H > HCAP): 50-round exact rescan
        uint64_t prev = ~0ull;
        for (int t = 0; t < target; ++t) {
            uint64_t best = 0;
            for (int gi = tid; gi < n; gi += 256) {
                int lo = 0, hi2 = GT;
                while (hi2 - lo > 1) { int mid = (lo + hi2) >> 1;
                                       if (toffs[mid] <= gi) lo = mid; else hi2 = mid; }
                uint64_t key = cb[(size_t)lo * LCAP + (gi - toffs[lo])];
                if (key < prev && key > best) best = key;
            }
            #pragma unroll
            for (int off = 32; off > 0; off >>= 1) {
                uint64_t o = __shfl_xor(best, off);
                if (o > best) best = o;
            }
            if ((tid & 63) == 0) wred[tid >> 6] = best;
            __syncthreads();
            if (tid == 0) {
                uint64_t w = wred[0];
                #pragma unroll
                for (int i = 1; i < 4; ++i) if (wred[i] > w) w = wred[i];
                bcast = w;
                sel_idx_s[t] = (int)(~(uint32_t)(w & 0xFFFFFFFFu));
                sel_valid_s[t] = 1;
            }
            __syncthreads();
            prev = bcast;
        }
    }
    __syncthreads();

    // dead fallback: <50 peaks -> ascending non-peak indices; none -> center
    if (tid == 0 && target < NSTORM) {
        const float* vb = vil + ((size_t)b * TFRAMES + (TFRAMES - 1)) * (HV * WV);
        int f = 0;
        for (int t = target; t < NSTORM; ++t) {
            while (f < HV * WV && is_peak(vb, f)) ++f;
            sel_idx_s[t] = f; sel_valid_s[t] = 0; ++f;
        }
        if (n == 0) { sel_idx_s[0] = (HV / 2) * WV + (WV / 2); sel_valid_s[0] = 1; }
    }
    __syncthreads();

    // positions / valid written once per batch (group 0 only)
    if (grp == 0 && tid < NSTORM) {
        int idx = sel_idx_s[tid], vld = sel_valid_s[tid];
        int y = idx / WV, x = idx % WV;
        int yf = y >> 2; if (yf > HF - 1) yf = HF - 1;
        int xf = x >> 2; if (xf > WF - 1) xf = WF - 1;
        float* pos_out   = out + (size_t)NB * NSTORM * NC;
        float* valid_out = pos_out + (size_t)NB * NSTORM * 2;
        pos_out[(b * NSTORM + tid) * 2 + 0] = (float)yf;
        pos_out[(b * NSTORM + tid) * 2 + 1] = (float)xf;
        valid_out[b * NSTORM + tid] = vld ? 1.f : 0.f;
    }

    // ---- project my 10 storms: gather (256 threads) + matvec (128)
    for (int q = tid; q < SPB * NC; q += 256) {
        int s = q >> 7, c = q & 127;
        int idx = sel_idx_s[grp * SPB + s];
        int y = idx / WV, x = idx % WV;
        int yf = y >> 2; if (yf > HF - 1) yf = HF - 1;
        int xf = x >> 2; if (xf > WF - 1) xf = WF - 1;
        g[s][c] = features[((size_t)b * NC + c) * (HF * WF) + yf * WF + xf];
    }
    __syncthreads();

    if (tid < NC) {
        int d = tid;
        const float4* w4 = (const float4*)(proj_w + (size_t)d * NC);
        float acc[SPB];
        #pragma unroll
        for (int s = 0; s < SPB; ++s) acc[s] = 0.f;
        for (int q = 0; q < 32; ++q) {
            float4 wv = w4[q];
            #pragma unroll
            for (int s = 0; s < SPB; ++s) {
                float4 gv = *(const float4*)&g[s][4 * q];
                acc[s] += gv.x * wv.x;
                acc[s] += gv.y * wv.y;
                acc[s] += gv.z * wv.z;
                acc[s] += gv.w * wv.w;
            }
        }
        float bias = proj_b[d];
        #pragma unroll
        for (int s = 0; s < SPB; ++s) {
            int m = grp * SPB + s;
            out[((size_t)b * NSTORM + m) * NC + d] =
                sel_valid_s[m] ? (acc[s] + bias) : 0.f;
        }
    }
}

extern "C" void kernel_launch(void* const* d_in, const int* in_sizes, int n_in,
                              void* d_out, int out_size, void* d_ws, size_t ws_size,
                              hipStream_t stream) {
    const float* features = (const float*)d_in[0];
    const float* vil      = (const float*)d_in[1];
    const float* proj_w   = (const float*)d_in[2];
    const float* proj_b   = (const float*)d_in[3];
    float* out = (float*)d_out;

    uint8_t* ws = (uint8_t*)d_ws;
    int* tcnt      = (int*)ws;                        // 32*72 ints, all written
    uint64_t* cand = (uint64_t*)(ws + 32768);         // 32*72*256 u64 = 4.7 MB

    dim3 gA(GX, GY, NB);                   // 6 x 12 x 32
    peak_kernel<<<gA, 256, 0, stream>>>(vil, cand, tcnt);
    select_project_kernel<<<NPROJ, 256, 0, stream>>>(cand, tcnt, vil, features,
                                                     proj_w, proj_b, out);
}